// Round 1
// baseline (412.914 us; speedup 1.0000x reference)
//
#include <hip/hip_runtime.h>
#include <math.h>

#define N_NODES 20000
#define N_EDGES 320000
#define IN_CH 512
#define HEADS 4
#define OUT_CH 128
#define HC 512            // HEADS*OUT_CH
#define NEG_SLOPE 0.2f

// ---------------- edge-index dtype detection ----------------
// Reference declares int64 edge_index; harness doc says int32. Detect on
// device: if the data is int64 (values < 2^31), every odd 32-bit word is 0.
__global__ void detect_kernel(const int* __restrict__ ei32, int* __restrict__ flag) {
    int is64 = 1;
    for (int i = 0; i < 64; i++) {
        if (ei32[2 * i + 1] != 0) { is64 = 0; break; }
    }
    *flag = is64;
}

__device__ __forceinline__ int edge_at(const void* ei, int is64, long long idx) {
    return is64 ? (int)((const long long*)ei)[idx] : ((const int*)ei)[idx];
}

// ---------------- fp32 tiled GEMM: C[M,N] = A[M,K] @ B[K,N] ----------------
// M=20000, K=512, N=512. 64x64 tile, BK=16, 256 threads, 4x4 microtile.
__global__ __launch_bounds__(256) void gemm_kernel(const float* __restrict__ A,
                                                   const float* __restrict__ B,
                                                   float* __restrict__ C) {
    __shared__ __align__(16) float As[16][68];   // [k][m], pad to 68 keeps 16B row alignment
    __shared__ __align__(16) float Bs[16][68];   // [k][n]
    const int bn = blockIdx.x * 64;
    const int bm = blockIdx.y * 64;
    const int tid = threadIdx.x;
    const int tx = tid & 15, ty = tid >> 4;

    // A staging: thread -> row bm + tid/4, k = k0 + (tid%4)*4 (float4)
    const int am = tid >> 2;
    const int ak = (tid & 3) * 4;
    // B staging: thread -> row k0 + tid/16, col bn + (tid%16)*4 (float4)
    const int bk = tid >> 4;
    const int bc = (tid & 15) * 4;

    float acc[4][4] = {};
    for (int k0 = 0; k0 < IN_CH; k0 += 16) {
        float4 av = make_float4(0.f, 0.f, 0.f, 0.f);
        int arow = bm + am;
        if (arow < N_NODES) av = *(const float4*)&A[(size_t)arow * IN_CH + k0 + ak];
        float4 bv = *(const float4*)&B[(size_t)(k0 + bk) * HC + bn + bc];
        __syncthreads();   // previous iteration's reads complete before overwrite
        As[ak + 0][am] = av.x; As[ak + 1][am] = av.y;
        As[ak + 2][am] = av.z; As[ak + 3][am] = av.w;
        *(float4*)&Bs[bk][bc] = bv;
        __syncthreads();
        #pragma unroll
        for (int kk = 0; kk < 16; kk++) {
            float4 a = *(float4*)&As[kk][ty * 4];
            float4 b = *(float4*)&Bs[kk][tx * 4];
            acc[0][0] += a.x * b.x; acc[0][1] += a.x * b.y; acc[0][2] += a.x * b.z; acc[0][3] += a.x * b.w;
            acc[1][0] += a.y * b.x; acc[1][1] += a.y * b.y; acc[1][2] += a.y * b.z; acc[1][3] += a.y * b.w;
            acc[2][0] += a.z * b.x; acc[2][1] += a.z * b.y; acc[2][2] += a.z * b.z; acc[2][3] += a.z * b.w;
            acc[3][0] += a.w * b.x; acc[3][1] += a.w * b.y; acc[3][2] += a.w * b.z; acc[3][3] += a.w * b.w;
        }
    }
    #pragma unroll
    for (int i = 0; i < 4; i++) {
        int row = bm + ty * 4 + i;
        if (row < N_NODES) {
            *(float4*)&C[(size_t)row * HC + bn + tx * 4] =
                make_float4(acc[i][0], acc[i][1], acc[i][2], acc[i][3]);
        }
    }
}

// ---------------- per-node attention halves: a_s[n,h], a_d[n,h] ----------------
__global__ __launch_bounds__(128) void attn_kernel(const float* __restrict__ xl,
                                                   const float* __restrict__ att_s,
                                                   const float* __restrict__ att_d,
                                                   float* __restrict__ a_s,
                                                   float* __restrict__ a_d) {
    int n = blockIdx.x;
    int c = threadIdx.x;          // 0..127
    int lane = c & 63, wv = c >> 6;
    __shared__ float red[2][4][2];
    #pragma unroll
    for (int h = 0; h < 4; h++) {
        float v = xl[(size_t)n * HC + h * OUT_CH + c];
        float s = v * att_s[h * OUT_CH + c];
        float d = v * att_d[h * OUT_CH + c];
        #pragma unroll
        for (int off = 32; off > 0; off >>= 1) {
            s += __shfl_down(s, off, 64);
            d += __shfl_down(d, off, 64);
        }
        if (lane == 0) { red[wv][h][0] = s; red[wv][h][1] = d; }
    }
    __syncthreads();
    if (c < 4) {
        a_s[n * 4 + c] = red[0][c][0] + red[1][c][0];
        a_d[n * 4 + c] = red[0][c][1] + red[1][c][1];
    }
}

// ---------------- CSR build: count, scan, scatter ----------------
__global__ __launch_bounds__(256) void count_kernel(const void* __restrict__ ei,
                                                    const int* __restrict__ flag,
                                                    int* __restrict__ counts) {
    int e = blockIdx.x * blockDim.x + threadIdx.x;
    if (e < N_EDGES) {
        int dst = edge_at(ei, *flag, (long long)N_EDGES + e);
        atomicAdd(&counts[dst], 1);
    }
}

__global__ __launch_bounds__(1024) void scan_kernel(const int* __restrict__ counts,
                                                    int* __restrict__ offsets) {
    __shared__ int lds[1024];
    __shared__ int carry;
    int tid = threadIdx.x;
    if (tid == 0) carry = 0;
    __syncthreads();
    for (int base = 0; base < N_NODES; base += 1024) {
        int i = base + tid;
        int v = (i < N_NODES) ? counts[i] : 0;
        lds[tid] = v;
        __syncthreads();
        for (int off = 1; off < 1024; off <<= 1) {
            int t = (tid >= off) ? lds[tid - off] : 0;
            __syncthreads();
            lds[tid] += t;
            __syncthreads();
        }
        if (i < N_NODES) offsets[i] = carry + lds[tid] - v;   // exclusive
        __syncthreads();
        if (tid == 0) carry += lds[1023];
        __syncthreads();
    }
    if (tid == 0) offsets[N_NODES] = carry;
}

__global__ __launch_bounds__(256) void scatter_kernel(const void* __restrict__ ei,
                                                      const int* __restrict__ flag,
                                                      const int* __restrict__ offsets,
                                                      int* __restrict__ cursor,
                                                      int* __restrict__ sorted_src) {
    int e = blockIdx.x * blockDim.x + threadIdx.x;
    if (e < N_EDGES) {
        int is64 = *flag;
        int dst = edge_at(ei, is64, (long long)N_EDGES + e);
        int src = edge_at(ei, is64, e);
        int pos = offsets[dst] + atomicAdd(&cursor[dst], 1);
        sorted_src[pos] = src;
    }
}

// ---------------- per-node segment softmax + weighted gather ----------------
// One wave (64 lanes) per node; 4 waves per block. Self-loop handled inline.
__global__ __launch_bounds__(256) void gather_kernel(const float* __restrict__ xl,
                                                     const float* __restrict__ a_s,
                                                     const float* __restrict__ a_d,
                                                     const int* __restrict__ offsets,
                                                     const int* __restrict__ sorted_src,
                                                     const float* __restrict__ bias,
                                                     float* __restrict__ out) {
    int node = blockIdx.x * 4 + (threadIdx.x >> 6);
    if (node >= N_NODES) return;
    int lane = threadIdx.x & 63;
    int beg = offsets[node], end = offsets[node + 1];

    float ad[4], as_self[4];
    #pragma unroll
    for (int h = 0; h < 4; h++) { ad[h] = a_d[node * 4 + h]; as_self[h] = a_s[node * 4 + h]; }

    // pass 1: per-head max logit (self-loop included)
    float m[4];
    #pragma unroll
    for (int h = 0; h < 4; h++) {
        float t = as_self[h] + ad[h];
        m[h] = t > 0.f ? t : NEG_SLOPE * t;
    }
    for (int p = beg + lane; p < end; p += 64) {
        int s = sorted_src[p];
        #pragma unroll
        for (int h = 0; h < 4; h++) {
            float t = a_s[s * 4 + h] + ad[h];
            t = t > 0.f ? t : NEG_SLOPE * t;
            m[h] = fmaxf(m[h], t);
        }
    }
    #pragma unroll
    for (int off = 32; off > 0; off >>= 1) {
        #pragma unroll
        for (int h = 0; h < 4; h++) m[h] = fmaxf(m[h], __shfl_xor(m[h], off, 64));
    }

    // pass 2: exp weights + feature accumulation (lane covers c = lane + 64*i)
    float acc[8] = {0, 0, 0, 0, 0, 0, 0, 0};
    float denom[4] = {0, 0, 0, 0};
    {   // self-loop
        float w[4];
        #pragma unroll
        for (int h = 0; h < 4; h++) {
            float t = as_self[h] + ad[h];
            t = t > 0.f ? t : NEG_SLOPE * t;
            w[h] = __expf(t - m[h]);
            denom[h] += w[h];
        }
        const float* xr = &xl[(size_t)node * HC];
        #pragma unroll
        for (int i = 0; i < 8; i++) { int c = lane + 64 * i; acc[i] += w[c >> 7] * xr[c]; }
    }
    for (int p = beg; p < end; p++) {
        int s = sorted_src[p];          // wave-uniform -> broadcast
        float w[4];
        #pragma unroll
        for (int h = 0; h < 4; h++) {
            float t = a_s[s * 4 + h] + ad[h];
            t = t > 0.f ? t : NEG_SLOPE * t;
            w[h] = __expf(t - m[h]);
            denom[h] += w[h];
        }
        const float* xr = &xl[(size_t)s * HC];
        #pragma unroll
        for (int i = 0; i < 8; i++) { int c = lane + 64 * i; acc[i] += w[c >> 7] * xr[c]; }
    }
    #pragma unroll
    for (int h = 0; h < 4; h++) denom[h] = 1.0f / (denom[h] + 1e-16f);
    // c = lane + 64*i -> head = i>>1, out col = lane (i even) / 64+lane (i odd)
    float o0 = 0.25f * (acc[0] * denom[0] + acc[2] * denom[1] + acc[4] * denom[2] + acc[6] * denom[3]) + bias[lane];
    float o1 = 0.25f * (acc[1] * denom[0] + acc[3] * denom[1] + acc[5] * denom[2] + acc[7] * denom[3]) + bias[64 + lane];
    o0 = o0 > 0.f ? o0 : expm1f(o0);
    o1 = o1 > 0.f ? o1 : expm1f(o1);
    out[(size_t)node * OUT_CH + lane] = o0;
    out[(size_t)node * OUT_CH + 64 + lane] = o1;
}

// ---------------- launch ----------------
extern "C" void kernel_launch(void* const* d_in, const int* in_sizes, int n_in,
                              void* d_out, int out_size, void* d_ws, size_t ws_size,
                              hipStream_t stream) {
    const float* x       = (const float*)d_in[0];
    const float* W       = (const float*)d_in[1];
    const float* att_src = (const float*)d_in[2];
    const float* att_dst = (const float*)d_in[3];
    const float* bias    = (const float*)d_in[4];
    const void*  ei      = d_in[5];
    float* out = (float*)d_out;

    char* ws = (char*)d_ws;
    size_t off = 0;
    float* xl      = (float*)(ws + off); off += (size_t)N_NODES * HC * sizeof(float);
    float* a_s     = (float*)(ws + off); off += (size_t)N_NODES * HEADS * sizeof(float);
    float* a_d     = (float*)(ws + off); off += (size_t)N_NODES * HEADS * sizeof(float);
    int* counts    = (int*)(ws + off);   off += (size_t)N_NODES * sizeof(int);
    int* cursor    = (int*)(ws + off);   off += (size_t)N_NODES * sizeof(int);   // contiguous with counts
    int* offsets   = (int*)(ws + off);   off += (size_t)(N_NODES + 1) * sizeof(int);
    off = (off + 15) & ~(size_t)15;
    int* sorted_src = (int*)(ws + off);  off += (size_t)N_EDGES * sizeof(int);
    int* flag      = (int*)(ws + off);   off += sizeof(int);

    hipMemsetAsync(counts, 0, 2u * N_NODES * sizeof(int), stream);   // counts + cursor
    detect_kernel<<<1, 1, 0, stream>>>((const int*)ei, flag);
    gemm_kernel<<<dim3(HC / 64, (N_NODES + 63) / 64), 256, 0, stream>>>(x, W, xl);
    attn_kernel<<<N_NODES, 128, 0, stream>>>(xl, att_src, att_dst, a_s, a_d);
    count_kernel<<<(N_EDGES + 255) / 256, 256, 0, stream>>>(ei, flag, counts);
    scan_kernel<<<1, 1024, 0, stream>>>(counts, offsets);
    scatter_kernel<<<(N_EDGES + 255) / 256, 256, 0, stream>>>(ei, flag, offsets, cursor, sorted_src);
    gather_kernel<<<(N_NODES + 3) / 4, 256, 0, stream>>>(xl, a_s, a_d, offsets, sorted_src, bias, out);
}

// Round 2
// 307.820 us; speedup vs baseline: 1.3414x; 1.3414x over previous
//
#include <hip/hip_runtime.h>
#include <math.h>

#define N_NODES 20000
#define N_PAD 20096            // N_NODES rounded up to 128 (GEMM M-tile)
#define N_EDGES 320000
#define IN_CH 512
#define HEADS 4
#define OUT_CH 128
#define HC 512                 // HEADS*OUT_CH
#define NEG_SLOPE 0.2f

typedef __attribute__((ext_vector_type(8))) short short8;
typedef __attribute__((ext_vector_type(4))) float float4v;

// ---------------- edge-index dtype detection ----------------
__global__ void detect_kernel(const int* __restrict__ ei32, int* __restrict__ flag) {
    int is64 = 1;
    for (int i = 0; i < 64; i++) {
        if (ei32[2 * i + 1] != 0) { is64 = 0; break; }
    }
    *flag = is64;
}

__device__ __forceinline__ int edge_at(const void* ei, int is64, long long idx) {
    return is64 ? (int)((const long long*)ei)[idx] : ((const int*)ei)[idx];
}

__device__ __forceinline__ unsigned short f2bf(float f) {
    union { float f; unsigned u; } v; v.f = f;
    unsigned r = v.u + 0x7fffu + ((v.u >> 16) & 1u);   // RNE
    return (unsigned short)(r >> 16);
}

// ---------------- convert x -> bf16 (padded rows zeroed) ----------------
__global__ __launch_bounds__(256) void convert_x_kernel(const float* __restrict__ x,
                                                        unsigned short* __restrict__ xb) {
    size_t i = ((size_t)blockIdx.x * 256 + threadIdx.x) * 8;
    if (i >= (size_t)N_PAD * IN_CH) return;
    unsigned short o[8];
    if (i < (size_t)N_NODES * IN_CH) {
        float4 f0 = *(const float4*)&x[i];
        float4 f1 = *(const float4*)&x[i + 4];
        o[0] = f2bf(f0.x); o[1] = f2bf(f0.y); o[2] = f2bf(f0.z); o[3] = f2bf(f0.w);
        o[4] = f2bf(f1.x); o[5] = f2bf(f1.y); o[6] = f2bf(f1.z); o[7] = f2bf(f1.w);
    } else {
        for (int k = 0; k < 8; k++) o[k] = 0;
    }
    *(short8*)&xb[i] = *(short8*)o;
}

// ---------------- convert W[K][N] -> Wt[N][K] bf16 (LDS transpose) ----------------
__global__ __launch_bounds__(256) void convert_w_kernel(const float* __restrict__ W,
                                                        unsigned short* __restrict__ Wt) {
    __shared__ float tile[64][65];
    int k0 = blockIdx.x * 64, n0 = blockIdx.y * 64;
    int t = threadIdx.x, r = t >> 6, c = t & 63;
    for (int rr = r; rr < 64; rr += 4)
        tile[rr][c] = W[(size_t)(k0 + rr) * HC + n0 + c];
    __syncthreads();
    for (int rr = r; rr < 64; rr += 4)
        Wt[(size_t)(n0 + rr) * IN_CH + k0 + c] = f2bf(tile[c][rr]);
}

// ---------------- bf16 MFMA GEMM: C[M,N] = A[M,K] @ Wt[N,K]^T ----------------
// m97 structure: BM=BN=128, BK=32, 256 threads (4 waves), 4x4 16x16x32 frags/wave,
// global_load_lds width 16, single LDS buffer, 2 barriers per K-step.
__global__ __launch_bounds__(256) void gemm_kernel(const unsigned short* __restrict__ A,
                                                   const unsigned short* __restrict__ Bt,
                                                   float* __restrict__ C) {
    __shared__ __align__(16) unsigned short As[128 * 32];
    __shared__ __align__(16) unsigned short Bs[128 * 32];
    const int bm = blockIdx.y * 128;
    const int bn = blockIdx.x * 128;
    const int t = threadIdx.x;
    const int wv = t >> 6, lane = t & 63;
    const int wm = wv & 1, wn = wv >> 1;
    const int lm = lane & 15, lk = lane >> 4;

    float4v acc[4][4];
    #pragma unroll
    for (int i = 0; i < 4; i++)
        #pragma unroll
        for (int j = 0; j < 4; j++) acc[i][j] = (float4v){0.f, 0.f, 0.f, 0.f};

    const int srow = t >> 2;            // 0..63 within a 64-row half
    const int skof = (t & 3) * 8;       // k element offset of this thread's 16B

    for (int k0 = 0; k0 < IN_CH; k0 += 32) {
        __syncthreads();   // previous iteration's ds_reads complete before overwrite
        #pragma unroll
        for (int q = 0; q < 2; q++) {
            const unsigned short* gA = A + (size_t)(bm + q * 64 + srow) * IN_CH + k0 + skof;
            const unsigned short* gB = Bt + (size_t)(bn + q * 64 + srow) * IN_CH + k0 + skof;
            __builtin_amdgcn_global_load_lds((const __attribute__((address_space(1))) void*)gA,
                                             (__attribute__((address_space(3))) void*)&As[q * 2048 + t * 8], 16, 0, 0);
            __builtin_amdgcn_global_load_lds((const __attribute__((address_space(1))) void*)gB,
                                             (__attribute__((address_space(3))) void*)&Bs[q * 2048 + t * 8], 16, 0, 0);
        }
        __syncthreads();   // drains vmcnt (staging complete)

        short8 af[4], bf[4];
        #pragma unroll
        for (int i = 0; i < 4; i++)
            af[i] = *(const short8*)&As[(wm * 64 + i * 16 + lm) * 32 + lk * 8];
        #pragma unroll
        for (int j = 0; j < 4; j++)
            bf[j] = *(const short8*)&Bs[(wn * 64 + j * 16 + lm) * 32 + lk * 8];
        #pragma unroll
        for (int i = 0; i < 4; i++)
            #pragma unroll
            for (int j = 0; j < 4; j++)
                acc[i][j] = __builtin_amdgcn_mfma_f32_16x16x32_bf16(af[i], bf[j], acc[i][j], 0, 0, 0);
    }

    // C/D layout: col = lane&15, row = (lane>>4)*4 + reg  [m89-verified]
    #pragma unroll
    for (int i = 0; i < 4; i++) {
        #pragma unroll
        for (int r = 0; r < 4; r++) {
            int row = bm + wm * 64 + i * 16 + lk * 4 + r;
            if (row < N_NODES) {
                #pragma unroll
                for (int j = 0; j < 4; j++) {
                    int col = bn + wn * 64 + j * 16 + lm;
                    C[(size_t)row * HC + col] = acc[i][j][r];
                }
            }
        }
    }
}

// ---------------- per-node attention halves: a_s[n,h], a_d[n,h] ----------------
__global__ __launch_bounds__(128) void attn_kernel(const float* __restrict__ xl,
                                                   const float* __restrict__ att_s,
                                                   const float* __restrict__ att_d,
                                                   float* __restrict__ a_s,
                                                   float* __restrict__ a_d) {
    int n = blockIdx.x;
    int c = threadIdx.x;          // 0..127
    int lane = c & 63, wv = c >> 6;
    __shared__ float red[2][4][2];
    #pragma unroll
    for (int h = 0; h < 4; h++) {
        float v = xl[(size_t)n * HC + h * OUT_CH + c];
        float s = v * att_s[h * OUT_CH + c];
        float d = v * att_d[h * OUT_CH + c];
        #pragma unroll
        for (int off = 32; off > 0; off >>= 1) {
            s += __shfl_down(s, off, 64);
            d += __shfl_down(d, off, 64);
        }
        if (lane == 0) { red[wv][h][0] = s; red[wv][h][1] = d; }
    }
    __syncthreads();
    if (c < 4) {
        a_s[n * 4 + c] = red[0][c][0] + red[1][c][0];
        a_d[n * 4 + c] = red[0][c][1] + red[1][c][1];
    }
}

// ---------------- CSR build: count, scan (shfl), scatter ----------------
__global__ __launch_bounds__(256) void count_kernel(const void* __restrict__ ei,
                                                    const int* __restrict__ flag,
                                                    int* __restrict__ counts) {
    int e = blockIdx.x * blockDim.x + threadIdx.x;
    if (e < N_EDGES) {
        int dst = edge_at(ei, *flag, (long long)N_EDGES + e);
        atomicAdd(&counts[dst], 1);
    }
}

__global__ __launch_bounds__(1024) void scan_kernel(const int* __restrict__ counts,
                                                    int* __restrict__ offsets) {
    __shared__ int wsum[16];
    __shared__ int carry;
    int tid = threadIdx.x, lane = tid & 63, wv = tid >> 6;
    if (tid == 0) carry = 0;
    __syncthreads();
    for (int base = 0; base < N_NODES; base += 1024) {
        int i = base + tid;
        int v = (i < N_NODES) ? counts[i] : 0;
        int s = v;
        #pragma unroll
        for (int off = 1; off < 64; off <<= 1) {
            int u = __shfl_up(s, off, 64);
            if (lane >= off) s += u;
        }
        if (lane == 63) wsum[wv] = s;
        __syncthreads();
        if (wv == 0 && lane < 16) {
            int u = wsum[lane];
            #pragma unroll
            for (int off = 1; off < 16; off <<= 1) {
                int w = __shfl_up(u, off, 64);
                if (lane >= off) u += w;
            }
            wsum[lane] = u;           // inclusive over wave sums
        }
        __syncthreads();
        int wbase = (wv == 0) ? 0 : wsum[wv - 1];
        if (i < N_NODES) offsets[i] = carry + wbase + s - v;   // exclusive
        __syncthreads();
        if (tid == 0) carry += wsum[15];
        __syncthreads();
    }
    if (tid == 0) offsets[N_NODES] = carry;
}

__global__ __launch_bounds__(256) void scatter_kernel(const void* __restrict__ ei,
                                                      const int* __restrict__ flag,
                                                      const int* __restrict__ offsets,
                                                      int* __restrict__ cursor,
                                                      int* __restrict__ sorted_src) {
    int e = blockIdx.x * blockDim.x + threadIdx.x;
    if (e < N_EDGES) {
        int is64 = *flag;
        int dst = edge_at(ei, is64, (long long)N_EDGES + e);
        int src = edge_at(ei, is64, e);
        int pos = offsets[dst] + atomicAdd(&cursor[dst], 1);
        sorted_src[pos] = src;
    }
}

// ---------------- per-node segment softmax + weighted gather ----------------
// One wave per node; lane owns channels c = lane*8..lane*8+7 => head = lane>>4.
__device__ __forceinline__ float leaky(float t) { return t > 0.f ? t : NEG_SLOPE * t; }

__global__ __launch_bounds__(256) void gather_kernel(const float* __restrict__ xl,
                                                     const float* __restrict__ a_s,
                                                     const float* __restrict__ a_d,
                                                     const int* __restrict__ offsets,
                                                     const int* __restrict__ sorted_src,
                                                     const float* __restrict__ bias,
                                                     float* __restrict__ out) {
    int node = blockIdx.x * 4 + (threadIdx.x >> 6);
    if (node >= N_NODES) return;
    int lane = threadIdx.x & 63;
    int hd = lane >> 4;
    int beg = offsets[node], end = offsets[node + 1];

    float4 asv = *(const float4*)&a_s[node * 4];
    float4 adv = *(const float4*)&a_d[node * 4];

    // pass 1: per-head max logit (lanes stride edges; self-loop seeds)
    float m0 = leaky(asv.x + adv.x), m1 = leaky(asv.y + adv.y);
    float m2 = leaky(asv.z + adv.z), m3 = leaky(asv.w + adv.w);
    for (int p = beg + lane; p < end; p += 64) {
        int s = sorted_src[p];
        float4 av = *(const float4*)&a_s[s * 4];
        m0 = fmaxf(m0, leaky(av.x + adv.x));
        m1 = fmaxf(m1, leaky(av.y + adv.y));
        m2 = fmaxf(m2, leaky(av.z + adv.z));
        m3 = fmaxf(m3, leaky(av.w + adv.w));
    }
    #pragma unroll
    for (int off = 32; off > 0; off >>= 1) {
        m0 = fmaxf(m0, __shfl_xor(m0, off, 64));
        m1 = fmaxf(m1, __shfl_xor(m1, off, 64));
        m2 = fmaxf(m2, __shfl_xor(m2, off, 64));
        m3 = fmaxf(m3, __shfl_xor(m3, off, 64));
    }
    float mh  = (hd & 2) ? ((hd & 1) ? m3 : m2) : ((hd & 1) ? m1 : m0);
    float adh = (hd & 2) ? ((hd & 1) ? adv.w : adv.z) : ((hd & 1) ? adv.y : adv.x);
    float ash = (hd & 2) ? ((hd & 1) ? asv.w : asv.z) : ((hd & 1) ? asv.y : asv.x);

    // pass 2: exp weights + float4 feature accumulation
    float acc[8];
    float denom;
    {
        float w = __expf(leaky(ash + adh) - mh);
        denom = w;
        const float4* xr = (const float4*)&xl[(size_t)node * HC + lane * 8];
        float4 f0 = xr[0], f1 = xr[1];
        acc[0] = w * f0.x; acc[1] = w * f0.y; acc[2] = w * f0.z; acc[3] = w * f0.w;
        acc[4] = w * f1.x; acc[5] = w * f1.y; acc[6] = w * f1.z; acc[7] = w * f1.w;
    }
    #pragma unroll 2
    for (int p = beg; p < end; ++p) {
        int s = sorted_src[p];
        float av = a_s[s * 4 + hd];
        float w = __expf(leaky(av + adh) - mh);
        denom += w;
        const float4* xr = (const float4*)&xl[(size_t)s * HC + lane * 8];
        float4 f0 = xr[0], f1 = xr[1];
        acc[0] += w * f0.x; acc[1] += w * f0.y; acc[2] += w * f0.z; acc[3] += w * f0.w;
        acc[4] += w * f1.x; acc[5] += w * f1.y; acc[6] += w * f1.z; acc[7] += w * f1.w;
    }
    float rd = 0.25f / (denom + 1e-16f);   // fold head-mean into the normalize
    float v[8];
    #pragma unroll
    for (int k = 0; k < 8; k++) {
        float t = acc[k] * rd;
        t += __shfl_xor(t, 16, 64);
        t += __shfl_xor(t, 32, 64);
        v[k] = t;
    }
    if (hd == 0) {   // lanes 0..15 hold the head-mean for channels lane*8..+7
        float4 b0 = *(const float4*)&bias[lane * 8];
        float4 b1 = *(const float4*)&bias[lane * 8 + 4];
        float o[8];
        o[0] = v[0] + b0.x; o[1] = v[1] + b0.y; o[2] = v[2] + b0.z; o[3] = v[3] + b0.w;
        o[4] = v[4] + b1.x; o[5] = v[5] + b1.y; o[6] = v[6] + b1.z; o[7] = v[7] + b1.w;
        #pragma unroll
        for (int k = 0; k < 8; k++) o[k] = o[k] > 0.f ? o[k] : expm1f(o[k]);
        *(float4*)&out[(size_t)node * OUT_CH + lane * 8]     = make_float4(o[0], o[1], o[2], o[3]);
        *(float4*)&out[(size_t)node * OUT_CH + lane * 8 + 4] = make_float4(o[4], o[5], o[6], o[7]);
    }
}

// ---------------- launch ----------------
extern "C" void kernel_launch(void* const* d_in, const int* in_sizes, int n_in,
                              void* d_out, int out_size, void* d_ws, size_t ws_size,
                              hipStream_t stream) {
    const float* x       = (const float*)d_in[0];
    const float* W       = (const float*)d_in[1];
    const float* att_src = (const float*)d_in[2];
    const float* att_dst = (const float*)d_in[3];
    const float* bias    = (const float*)d_in[4];
    const void*  ei      = d_in[5];
    float* out = (float*)d_out;

    char* ws = (char*)d_ws;
    size_t off = 0;
    float* xl      = (float*)(ws + off); off += (size_t)N_NODES * HC * sizeof(float);
    float* a_s     = (float*)(ws + off); off += (size_t)N_NODES * HEADS * sizeof(float);
    float* a_d     = (float*)(ws + off); off += (size_t)N_NODES * HEADS * sizeof(float);
    int* counts    = (int*)(ws + off);   off += (size_t)N_NODES * sizeof(int);
    int* cursor    = (int*)(ws + off);   off += (size_t)N_NODES * sizeof(int);   // contiguous with counts
    int* offsets   = (int*)(ws + off);   off += (size_t)(N_NODES + 1) * sizeof(int);
    off = (off + 15) & ~(size_t)15;
    int* sorted_src = (int*)(ws + off);  off += (size_t)N_EDGES * sizeof(int);
    int* flag      = (int*)(ws + off);   off += sizeof(int);
    off = (off + 15) & ~(size_t)15;
    unsigned short* xb = (unsigned short*)(ws + off); off += (size_t)N_PAD * IN_CH * sizeof(unsigned short);
    unsigned short* Wt = (unsigned short*)(ws + off); off += (size_t)IN_CH * HC * sizeof(unsigned short);

    hipMemsetAsync(counts, 0, 2u * N_NODES * sizeof(int), stream);   // counts + cursor
    detect_kernel<<<1, 1, 0, stream>>>((const int*)ei, flag);
    convert_x_kernel<<<(int)(((size_t)N_PAD * IN_CH / 8 + 255) / 256), 256, 0, stream>>>(x, xb);
    convert_w_kernel<<<dim3(IN_CH / 64, HC / 64), 256, 0, stream>>>(W, Wt);
    gemm_kernel<<<dim3(HC / 128, N_PAD / 128), 256, 0, stream>>>(xb, Wt, xl);
    attn_kernel<<<N_NODES, 128, 0, stream>>>(xl, att_src, att_dst, a_s, a_d);
    count_kernel<<<(N_EDGES + 255) / 256, 256, 0, stream>>>(ei, flag, counts);
    scan_kernel<<<1, 1024, 0, stream>>>(counts, offsets);
    scatter_kernel<<<(N_EDGES + 255) / 256, 256, 0, stream>>>(ei, flag, offsets, cursor, sorted_src);
    gather_kernel<<<(N_NODES + 3) / 4, 256, 0, stream>>>(xl, a_s, a_d, offsets, sorted_src, bias, out);
}

// Round 3
// 232.123 us; speedup vs baseline: 1.7789x; 1.3261x over previous
//
#include <hip/hip_runtime.h>
#include <math.h>

#define N_NODES 20000
#define N_PAD 20096            // N_NODES rounded up to 128 (GEMM M-tile)
#define N_EDGES 320000
#define IN_CH 512
#define HEADS 4
#define OUT_CH 128
#define HC 512                 // HEADS*OUT_CH
#define NEG_SLOPE 0.2f

typedef __attribute__((ext_vector_type(8))) short short8;
typedef __attribute__((ext_vector_type(4))) float float4v;

// ---------------- edge-index dtype detection ----------------
__global__ void detect_kernel(const int* __restrict__ ei32, int* __restrict__ flag) {
    int is64 = 1;
    for (int i = 0; i < 64; i++) {
        if (ei32[2 * i + 1] != 0) { is64 = 0; break; }
    }
    *flag = is64;
}

__device__ __forceinline__ int edge_at(const void* ei, int is64, long long idx) {
    return is64 ? (int)((const long long*)ei)[idx] : ((const int*)ei)[idx];
}

__device__ __forceinline__ unsigned short f2bf(float f) {
    union { float f; unsigned u; } v; v.f = f;
    unsigned r = v.u + 0x7fffu + ((v.u >> 16) & 1u);   // RNE
    return (unsigned short)(r >> 16);
}

// decode 8 packed bf16 (uint4) -> 8 floats
__device__ __forceinline__ void bf8_decode(uint4 r, float* f) {
    f[0] = __uint_as_float(r.x << 16); f[1] = __uint_as_float(r.x & 0xffff0000u);
    f[2] = __uint_as_float(r.y << 16); f[3] = __uint_as_float(r.y & 0xffff0000u);
    f[4] = __uint_as_float(r.z << 16); f[5] = __uint_as_float(r.z & 0xffff0000u);
    f[6] = __uint_as_float(r.w << 16); f[7] = __uint_as_float(r.w & 0xffff0000u);
}

// ---------------- convert x -> bf16 (padded rows zeroed) ----------------
__global__ __launch_bounds__(256) void convert_x_kernel(const float* __restrict__ x,
                                                        unsigned short* __restrict__ xb) {
    size_t i = ((size_t)blockIdx.x * 256 + threadIdx.x) * 8;
    if (i >= (size_t)N_PAD * IN_CH) return;
    unsigned short o[8];
    if (i < (size_t)N_NODES * IN_CH) {
        float4 f0 = *(const float4*)&x[i];
        float4 f1 = *(const float4*)&x[i + 4];
        o[0] = f2bf(f0.x); o[1] = f2bf(f0.y); o[2] = f2bf(f0.z); o[3] = f2bf(f0.w);
        o[4] = f2bf(f1.x); o[5] = f2bf(f1.y); o[6] = f2bf(f1.z); o[7] = f2bf(f1.w);
    } else {
        for (int k = 0; k < 8; k++) o[k] = 0;
    }
    *(short8*)&xb[i] = *(short8*)o;
}

// ---------------- convert W[K][N] -> Wt[N][K] bf16 (LDS transpose) ----------------
__global__ __launch_bounds__(256) void convert_w_kernel(const float* __restrict__ W,
                                                        unsigned short* __restrict__ Wt) {
    __shared__ float tile[64][65];
    int k0 = blockIdx.x * 64, n0 = blockIdx.y * 64;
    int t = threadIdx.x, r = t >> 6, c = t & 63;
    for (int rr = r; rr < 64; rr += 4)
        tile[rr][c] = W[(size_t)(k0 + rr) * HC + n0 + c];
    __syncthreads();
    for (int rr = r; rr < 64; rr += 4)
        Wt[(size_t)(n0 + rr) * IN_CH + k0 + c] = f2bf(tile[c][rr]);
}

// ---------------- bf16 MFMA GEMM: xlb[M,N](bf16) = A[M,K] @ Wt[N,K]^T ----------------
__global__ __launch_bounds__(256) void gemm_kernel(const unsigned short* __restrict__ A,
                                                   const unsigned short* __restrict__ Bt,
                                                   unsigned short* __restrict__ Cb) {
    __shared__ __align__(16) unsigned short As[128 * 32];
    __shared__ __align__(16) unsigned short Bs[128 * 32];
    const int bm = blockIdx.y * 128;
    const int bn = blockIdx.x * 128;
    const int t = threadIdx.x;
    const int wv = t >> 6, lane = t & 63;
    const int wm = wv & 1, wn = wv >> 1;
    const int lm = lane & 15, lk = lane >> 4;

    float4v acc[4][4];
    #pragma unroll
    for (int i = 0; i < 4; i++)
        #pragma unroll
        for (int j = 0; j < 4; j++) acc[i][j] = (float4v){0.f, 0.f, 0.f, 0.f};

    const int srow = t >> 2;            // 0..63 within a 64-row half
    const int skof = (t & 3) * 8;       // k element offset of this thread's 16B

    for (int k0 = 0; k0 < IN_CH; k0 += 32) {
        __syncthreads();
        #pragma unroll
        for (int q = 0; q < 2; q++) {
            const unsigned short* gA = A + (size_t)(bm + q * 64 + srow) * IN_CH + k0 + skof;
            const unsigned short* gB = Bt + (size_t)(bn + q * 64 + srow) * IN_CH + k0 + skof;
            __builtin_amdgcn_global_load_lds((const __attribute__((address_space(1))) void*)gA,
                                             (__attribute__((address_space(3))) void*)&As[q * 2048 + t * 8], 16, 0, 0);
            __builtin_amdgcn_global_load_lds((const __attribute__((address_space(1))) void*)gB,
                                             (__attribute__((address_space(3))) void*)&Bs[q * 2048 + t * 8], 16, 0, 0);
        }
        __syncthreads();

        short8 af[4], bf[4];
        #pragma unroll
        for (int i = 0; i < 4; i++)
            af[i] = *(const short8*)&As[(wm * 64 + i * 16 + lm) * 32 + lk * 8];
        #pragma unroll
        for (int j = 0; j < 4; j++)
            bf[j] = *(const short8*)&Bs[(wn * 64 + j * 16 + lm) * 32 + lk * 8];
        #pragma unroll
        for (int i = 0; i < 4; i++)
            #pragma unroll
            for (int j = 0; j < 4; j++)
                acc[i][j] = __builtin_amdgcn_mfma_f32_16x16x32_bf16(af[i], bf[j], acc[i][j], 0, 0, 0);
    }

    // C/D layout: col = lane&15, row = (lane>>4)*4 + reg
    #pragma unroll
    for (int i = 0; i < 4; i++) {
        #pragma unroll
        for (int r = 0; r < 4; r++) {
            int row = bm + wm * 64 + i * 16 + lk * 4 + r;
            if (row < N_NODES) {
                #pragma unroll
                for (int j = 0; j < 4; j++) {
                    int col = bn + wn * 64 + j * 16 + lm;
                    Cb[(size_t)row * HC + col] = f2bf(acc[i][j][r]);
                }
            }
        }
    }
}

// ---------------- per-node attention halves (wave per node, bf16 xl) ----------------
__global__ __launch_bounds__(256) void attn_kernel(const unsigned short* __restrict__ xlb,
                                                   const float* __restrict__ att_s,
                                                   const float* __restrict__ att_d,
                                                   float* __restrict__ a_s,
                                                   float* __restrict__ a_d) {
    int node = blockIdx.x * 4 + (threadIdx.x >> 6);
    if (node >= N_NODES) return;
    int lane = threadIdx.x & 63;
    int hd = lane >> 4;
    uint4 r = *(const uint4*)&xlb[(size_t)node * HC + lane * 8];
    float f[8];
    bf8_decode(r, f);
    float4 s0 = *(const float4*)&att_s[lane * 8];
    float4 s1 = *(const float4*)&att_s[lane * 8 + 4];
    float4 d0 = *(const float4*)&att_d[lane * 8];
    float4 d1 = *(const float4*)&att_d[lane * 8 + 4];
    float s = f[0]*s0.x + f[1]*s0.y + f[2]*s0.z + f[3]*s0.w
            + f[4]*s1.x + f[5]*s1.y + f[6]*s1.z + f[7]*s1.w;
    float d = f[0]*d0.x + f[1]*d0.y + f[2]*d0.z + f[3]*d0.w
            + f[4]*d1.x + f[5]*d1.y + f[6]*d1.z + f[7]*d1.w;
    #pragma unroll
    for (int off = 1; off < 16; off <<= 1) {
        s += __shfl_xor(s, off, 64);
        d += __shfl_xor(d, off, 64);
    }
    if ((lane & 15) == 0) {
        a_s[node * 4 + hd] = s;
        a_d[node * 4 + hd] = d;
    }
}

// ---------------- CSR build: count, chunked scan, scatter ----------------
__global__ __launch_bounds__(256) void count_kernel(const void* __restrict__ ei,
                                                    const int* __restrict__ flag,
                                                    int* __restrict__ counts) {
    int e = blockIdx.x * blockDim.x + threadIdx.x;
    if (e < N_EDGES) {
        int dst = edge_at(ei, *flag, (long long)N_EDGES + e);
        atomicAdd(&counts[dst], 1);
    }
}

// Each thread owns CHUNK=20 contiguous counts: local prefix, one block scan, write back.
__global__ __launch_bounds__(1024) void scan_kernel(const int* __restrict__ counts,
                                                    int* __restrict__ offsets) {
    const int CHUNK = 20;                 // 1024*20 = 20480 >= N_NODES
    int tid = threadIdx.x;
    int base = tid * CHUNK;
    int c[CHUNK];
    #pragma unroll
    for (int k = 0; k < CHUNK; k++) {
        int i = base + k;
        c[k] = (i < N_NODES) ? counts[i] : 0;
    }
    int pre[CHUNK];
    int sum = 0;
    #pragma unroll
    for (int k = 0; k < CHUNK; k++) { pre[k] = sum; sum += c[k]; }

    int lane = tid & 63, wv = tid >> 6;
    int s = sum;
    #pragma unroll
    for (int off = 1; off < 64; off <<= 1) {
        int u = __shfl_up(s, off, 64);
        if (lane >= off) s += u;
    }
    __shared__ int wsum[16];
    if (lane == 63) wsum[wv] = s;
    __syncthreads();
    if (tid < 16) {
        int u = wsum[tid];
        #pragma unroll
        for (int off = 1; off < 16; off <<= 1) {
            int w = __shfl_up(u, off, 64);
            if (tid >= off) u += w;
        }
        wsum[tid] = u;                    // inclusive over wave sums
    }
    __syncthreads();
    int wbase = (wv == 0) ? 0 : wsum[wv - 1];
    int excl = wbase + s - sum;           // exclusive prefix of this thread's chunk
    #pragma unroll
    for (int k = 0; k < CHUNK; k++) {
        int i = base + k;
        if (i < N_NODES) offsets[i] = excl + pre[k];
    }
    if (tid == 1023) offsets[N_NODES] = wbase + s;   // grand total
}

__global__ __launch_bounds__(256) void scatter_kernel(const void* __restrict__ ei,
                                                      const int* __restrict__ flag,
                                                      const int* __restrict__ offsets,
                                                      int* __restrict__ cursor,
                                                      int* __restrict__ sorted_src) {
    int e = blockIdx.x * blockDim.x + threadIdx.x;
    if (e < N_EDGES) {
        int is64 = *flag;
        int dst = edge_at(ei, is64, (long long)N_EDGES + e);
        int src = edge_at(ei, is64, e);
        int pos = offsets[dst] + atomicAdd(&cursor[dst], 1);
        sorted_src[pos] = src;
    }
}

// ---------------- single-pass segment softmax + weighted gather (bf16 xl) ----------------
// No max subtraction: logits bounded (~|7|), exp() safe in fp32, mathematically
// identical to the max-shifted form. One wave per node; lane owns channels
// lane*8..+7 => head = lane>>4.
__device__ __forceinline__ float leaky(float t) { return t > 0.f ? t : NEG_SLOPE * t; }

__global__ __launch_bounds__(256) void gather_kernel(const unsigned short* __restrict__ xlb,
                                                     const float* __restrict__ a_s,
                                                     const float* __restrict__ a_d,
                                                     const int* __restrict__ offsets,
                                                     const int* __restrict__ sorted_src,
                                                     const float* __restrict__ bias,
                                                     float* __restrict__ out) {
    int node = blockIdx.x * 4 + (threadIdx.x >> 6);
    if (node >= N_NODES) return;
    int lane = threadIdx.x & 63;
    int hd = lane >> 4;
    int beg = offsets[node], end = offsets[node + 1];

    float adh = a_d[node * 4 + hd];
    float acc[8];
    float denom;
    {   // self-loop
        float w = __expf(leaky(a_s[node * 4 + hd] + adh));
        denom = w;
        uint4 r = *(const uint4*)&xlb[(size_t)node * HC + lane * 8];
        float f[8];
        bf8_decode(r, f);
        #pragma unroll
        for (int k = 0; k < 8; k++) acc[k] = w * f[k];
    }
    int p = beg;
    for (; p + 2 <= end; p += 2) {
        int s0 = sorted_src[p];
        int s1 = sorted_src[p + 1];
        uint4 r0 = *(const uint4*)&xlb[(size_t)s0 * HC + lane * 8];
        uint4 r1 = *(const uint4*)&xlb[(size_t)s1 * HC + lane * 8];
        float w0 = __expf(leaky(a_s[s0 * 4 + hd] + adh));
        float w1 = __expf(leaky(a_s[s1 * 4 + hd] + adh));
        denom += w0 + w1;
        float f0[8], f1[8];
        bf8_decode(r0, f0);
        bf8_decode(r1, f1);
        #pragma unroll
        for (int k = 0; k < 8; k++) acc[k] += w0 * f0[k] + w1 * f1[k];
    }
    if (p < end) {
        int s0 = sorted_src[p];
        uint4 r0 = *(const uint4*)&xlb[(size_t)s0 * HC + lane * 8];
        float w0 = __expf(leaky(a_s[s0 * 4 + hd] + adh));
        denom += w0;
        float f0[8];
        bf8_decode(r0, f0);
        #pragma unroll
        for (int k = 0; k < 8; k++) acc[k] += w0 * f0[k];
    }

    float rd = 0.25f / (denom + 1e-16f);   // fold head-mean into normalize
    float v[8];
    #pragma unroll
    for (int k = 0; k < 8; k++) {
        float t = acc[k] * rd;
        t += __shfl_xor(t, 16, 64);
        t += __shfl_xor(t, 32, 64);
        v[k] = t;
    }
    if (hd == 0) {   // lanes 0..15 hold head-mean for channels lane*8..+7
        float4 b0 = *(const float4*)&bias[lane * 8];
        float4 b1 = *(const float4*)&bias[lane * 8 + 4];
        float o[8];
        o[0] = v[0] + b0.x; o[1] = v[1] + b0.y; o[2] = v[2] + b0.z; o[3] = v[3] + b0.w;
        o[4] = v[4] + b1.x; o[5] = v[5] + b1.y; o[6] = v[6] + b1.z; o[7] = v[7] + b1.w;
        #pragma unroll
        for (int k = 0; k < 8; k++) o[k] = o[k] > 0.f ? o[k] : expm1f(o[k]);
        *(float4*)&out[(size_t)node * OUT_CH + lane * 8]     = make_float4(o[0], o[1], o[2], o[3]);
        *(float4*)&out[(size_t)node * OUT_CH + lane * 8 + 4] = make_float4(o[4], o[5], o[6], o[7]);
    }
}

// ---------------- launch ----------------
extern "C" void kernel_launch(void* const* d_in, const int* in_sizes, int n_in,
                              void* d_out, int out_size, void* d_ws, size_t ws_size,
                              hipStream_t stream) {
    const float* x       = (const float*)d_in[0];
    const float* W       = (const float*)d_in[1];
    const float* att_src = (const float*)d_in[2];
    const float* att_dst = (const float*)d_in[3];
    const float* bias    = (const float*)d_in[4];
    const void*  ei      = d_in[5];
    float* out = (float*)d_out;

    char* ws = (char*)d_ws;
    size_t off = 0;
    unsigned short* xlb = (unsigned short*)(ws + off); off += (size_t)N_PAD * HC * sizeof(unsigned short);
    float* a_s     = (float*)(ws + off); off += (size_t)N_NODES * HEADS * sizeof(float);
    float* a_d     = (float*)(ws + off); off += (size_t)N_NODES * HEADS * sizeof(float);
    int* counts    = (int*)(ws + off);   off += (size_t)N_NODES * sizeof(int);
    int* cursor    = (int*)(ws + off);   off += (size_t)N_NODES * sizeof(int);   // contiguous with counts
    int* offsets   = (int*)(ws + off);   off += (size_t)(N_NODES + 1) * sizeof(int);
    off = (off + 15) & ~(size_t)15;
    int* sorted_src = (int*)(ws + off);  off += (size_t)N_EDGES * sizeof(int);
    int* flag      = (int*)(ws + off);   off += sizeof(int);
    off = (off + 15) & ~(size_t)15;
    unsigned short* xb = (unsigned short*)(ws + off); off += (size_t)N_PAD * IN_CH * sizeof(unsigned short);
    unsigned short* Wt = (unsigned short*)(ws + off); off += (size_t)IN_CH * HC * sizeof(unsigned short);

    hipMemsetAsync(counts, 0, 2u * N_NODES * sizeof(int), stream);   // counts + cursor
    detect_kernel<<<1, 1, 0, stream>>>((const int*)ei, flag);
    convert_x_kernel<<<(int)(((size_t)N_PAD * IN_CH / 8 + 255) / 256), 256, 0, stream>>>(x, xb);
    convert_w_kernel<<<dim3(IN_CH / 64, HC / 64), 256, 0, stream>>>(W, Wt);
    gemm_kernel<<<dim3(HC / 128, N_PAD / 128), 256, 0, stream>>>(xb, Wt, xlb);
    attn_kernel<<<(N_NODES + 3) / 4, 256, 0, stream>>>(xlb, att_src, att_dst, a_s, a_d);
    count_kernel<<<(N_EDGES + 255) / 256, 256, 0, stream>>>(ei, flag, counts);
    scan_kernel<<<1, 1024, 0, stream>>>(counts, offsets);
    scatter_kernel<<<(N_EDGES + 255) / 256, 256, 0, stream>>>(ei, flag, offsets, cursor, sorted_src);
    gather_kernel<<<(N_NODES + 3) / 4, 256, 0, stream>>>(xlb, a_s, a_d, offsets, sorted_src, bias, out);
}

// Round 4
// 216.921 us; speedup vs baseline: 1.9035x; 1.0701x over previous
//
#include <hip/hip_runtime.h>
#include <math.h>

#define N_NODES 20000
#define N_PAD 20096            // N_NODES rounded up to 128 (GEMM M-tile)
#define N_EDGES 320000
#define IN_CH 512
#define HEADS 4
#define OUT_CH 128
#define HC 512                 // HEADS*OUT_CH
#define NEG_SLOPE 0.2f

// fused-kernel block partitions
#define CVX_BLOCKS 5024        // N_PAD*IN_CH/8/256
#define CVW_BLOCKS 64          // (IN_CH/64)*(HC/64)
#define CNT_BLOCKS 1250        // N_EDGES/256
#define SCT_BLOCKS 1250
#define ATT_BLOCKS 5000        // N_NODES/4

typedef __attribute__((ext_vector_type(8))) short short8;
typedef __attribute__((ext_vector_type(4))) float float4v;

// ---------------- edge-index dtype detection (inline, deterministic) ----------------
// int64 layout: odd 32-bit words are the high halves of values < 2^31 -> all 0.
// int32 layout: odd words are random node ids; P(32 consecutive odd words all 0) ~ 0.
// Addresses are thread-uniform -> compiler emits s_load; cost is negligible.
__device__ __forceinline__ int detect_is64(const int* __restrict__ ei32) {
    int is64 = 1;
    #pragma unroll
    for (int i = 0; i < 32; i++) is64 &= (ei32[2 * i + 1] == 0);
    return is64;
}

__device__ __forceinline__ int edge_at(const void* ei, int is64, long long idx) {
    return is64 ? (int)((const long long*)ei)[idx] : ((const int*)ei)[idx];
}

__device__ __forceinline__ unsigned short f2bf(float f) {
    union { float f; unsigned u; } v; v.f = f;
    unsigned r = v.u + 0x7fffu + ((v.u >> 16) & 1u);   // RNE
    return (unsigned short)(r >> 16);
}

// decode 8 packed bf16 (uint4) -> 8 floats (1 VALU op per element)
__device__ __forceinline__ void bf8_decode(uint4 r, float* f) {
    f[0] = __uint_as_float(r.x << 16); f[1] = __uint_as_float(r.x & 0xffff0000u);
    f[2] = __uint_as_float(r.y << 16); f[3] = __uint_as_float(r.y & 0xffff0000u);
    f[4] = __uint_as_float(r.z << 16); f[5] = __uint_as_float(r.z & 0xffff0000u);
    f[6] = __uint_as_float(r.w << 16); f[7] = __uint_as_float(r.w & 0xffff0000u);
}

__device__ __forceinline__ float leaky(float t) { return t > 0.f ? t : NEG_SLOPE * t; }

// ---------------- K1: fused convert_x + convert_w(transpose) + count ----------------
__global__ __launch_bounds__(256) void fusedA_kernel(const float* __restrict__ x,
                                                     const float* __restrict__ W,
                                                     unsigned short* __restrict__ xb,
                                                     unsigned short* __restrict__ Wt,
                                                     const void* __restrict__ ei,
                                                     int* __restrict__ counts) {
    __shared__ float tile[64][65];     // used by convert_w branch only
    int b = blockIdx.x;
    if (b < CVX_BLOCKS) {
        // ---- convert x -> bf16 (padded rows zeroed) ----
        size_t i = ((size_t)b * 256 + threadIdx.x) * 8;
        unsigned short o[8];
        if (i < (size_t)N_NODES * IN_CH) {
            float4 f0 = *(const float4*)&x[i];
            float4 f1 = *(const float4*)&x[i + 4];
            o[0] = f2bf(f0.x); o[1] = f2bf(f0.y); o[2] = f2bf(f0.z); o[3] = f2bf(f0.w);
            o[4] = f2bf(f1.x); o[5] = f2bf(f1.y); o[6] = f2bf(f1.z); o[7] = f2bf(f1.w);
        } else {
            for (int k = 0; k < 8; k++) o[k] = 0;
        }
        *(short8*)&xb[i] = *(short8*)o;
    } else if (b < CVX_BLOCKS + CVW_BLOCKS) {
        // ---- W[K][N] -> Wt[N][K] bf16 via LDS transpose ----
        int idx = b - CVX_BLOCKS;
        int k0 = (idx & 7) * 64, n0 = (idx >> 3) * 64;
        int t = threadIdx.x, r = t >> 6, c = t & 63;
        for (int rr = r; rr < 64; rr += 4)
            tile[rr][c] = W[(size_t)(k0 + rr) * HC + n0 + c];
        __syncthreads();
        for (int rr = r; rr < 64; rr += 4)
            Wt[(size_t)(n0 + rr) * IN_CH + k0 + c] = f2bf(tile[c][rr]);
    } else {
        // ---- count incoming edges per dst ----
        int is64 = detect_is64((const int*)ei);
        int e = (b - CVX_BLOCKS - CVW_BLOCKS) * 256 + threadIdx.x;
        if (e < N_EDGES) {
            int dst = edge_at(ei, is64, (long long)N_EDGES + e);
            atomicAdd(&counts[dst], 1);
        }
    }
}

// ---------------- bf16 MFMA GEMM: xlb[M,N](bf16) = A[M,K] @ Wt[N,K]^T ----------------
__global__ __launch_bounds__(256) void gemm_kernel(const unsigned short* __restrict__ A,
                                                   const unsigned short* __restrict__ Bt,
                                                   unsigned short* __restrict__ Cb) {
    __shared__ __align__(16) unsigned short As[128 * 32];
    __shared__ __align__(16) unsigned short Bs[128 * 32];
    const int bm = blockIdx.y * 128;
    const int bn = blockIdx.x * 128;
    const int t = threadIdx.x;
    const int wv = t >> 6, lane = t & 63;
    const int wm = wv & 1, wn = wv >> 1;
    const int lm = lane & 15, lk = lane >> 4;

    float4v acc[4][4];
    #pragma unroll
    for (int i = 0; i < 4; i++)
        #pragma unroll
        for (int j = 0; j < 4; j++) acc[i][j] = (float4v){0.f, 0.f, 0.f, 0.f};

    const int srow = t >> 2;
    const int skof = (t & 3) * 8;

    for (int k0 = 0; k0 < IN_CH; k0 += 32) {
        __syncthreads();
        #pragma unroll
        for (int q = 0; q < 2; q++) {
            const unsigned short* gA = A + (size_t)(bm + q * 64 + srow) * IN_CH + k0 + skof;
            const unsigned short* gB = Bt + (size_t)(bn + q * 64 + srow) * IN_CH + k0 + skof;
            __builtin_amdgcn_global_load_lds((const __attribute__((address_space(1))) void*)gA,
                                             (__attribute__((address_space(3))) void*)&As[q * 2048 + t * 8], 16, 0, 0);
            __builtin_amdgcn_global_load_lds((const __attribute__((address_space(1))) void*)gB,
                                             (__attribute__((address_space(3))) void*)&Bs[q * 2048 + t * 8], 16, 0, 0);
        }
        __syncthreads();

        short8 af[4], bf[4];
        #pragma unroll
        for (int i = 0; i < 4; i++)
            af[i] = *(const short8*)&As[(wm * 64 + i * 16 + lm) * 32 + lk * 8];
        #pragma unroll
        for (int j = 0; j < 4; j++)
            bf[j] = *(const short8*)&Bs[(wn * 64 + j * 16 + lm) * 32 + lk * 8];
        #pragma unroll
        for (int i = 0; i < 4; i++)
            #pragma unroll
            for (int j = 0; j < 4; j++)
                acc[i][j] = __builtin_amdgcn_mfma_f32_16x16x32_bf16(af[i], bf[j], acc[i][j], 0, 0, 0);
    }

    // C/D layout: col = lane&15, row = (lane>>4)*4 + reg
    #pragma unroll
    for (int i = 0; i < 4; i++) {
        #pragma unroll
        for (int r = 0; r < 4; r++) {
            int row = bm + wm * 64 + i * 16 + lk * 4 + r;
            if (row < N_NODES) {
                #pragma unroll
                for (int j = 0; j < 4; j++) {
                    int col = bn + wn * 64 + j * 16 + lm;
                    Cb[(size_t)row * HC + col] = f2bf(acc[i][j][r]);
                }
            }
        }
    }
}

// ---------------- chunked block scan: counts -> exclusive offsets ----------------
__global__ __launch_bounds__(1024) void scan_kernel(const int* __restrict__ counts,
                                                    int* __restrict__ offsets) {
    const int CHUNK = 20;                 // 1024*20 = 20480 >= N_NODES
    int tid = threadIdx.x;
    int base = tid * CHUNK;
    int c[CHUNK];
    #pragma unroll
    for (int k = 0; k < CHUNK; k++) {
        int i = base + k;
        c[k] = (i < N_NODES) ? counts[i] : 0;
    }
    int pre[CHUNK];
    int sum = 0;
    #pragma unroll
    for (int k = 0; k < CHUNK; k++) { pre[k] = sum; sum += c[k]; }

    int lane = tid & 63, wv = tid >> 6;
    int s = sum;
    #pragma unroll
    for (int off = 1; off < 64; off <<= 1) {
        int u = __shfl_up(s, off, 64);
        if (lane >= off) s += u;
    }
    __shared__ int wsum[16];
    if (lane == 63) wsum[wv] = s;
    __syncthreads();
    if (tid < 16) {
        int u = wsum[tid];
        #pragma unroll
        for (int off = 1; off < 16; off <<= 1) {
            int w = __shfl_up(u, off, 64);
            if (tid >= off) u += w;
        }
        wsum[tid] = u;
    }
    __syncthreads();
    int wbase = (wv == 0) ? 0 : wsum[wv - 1];
    int excl = wbase + s - sum;
    #pragma unroll
    for (int k = 0; k < CHUNK; k++) {
        int i = base + k;
        if (i < N_NODES) offsets[i] = excl + pre[k];
    }
    if (tid == 1023) offsets[N_NODES] = wbase + s;
}

// ---------------- K4: fused scatter + attention halves ----------------
__global__ __launch_bounds__(256) void fusedB_kernel(const void* __restrict__ ei,
                                                     const int* __restrict__ offsets,
                                                     int* __restrict__ cursor,
                                                     int* __restrict__ sorted_src,
                                                     const unsigned short* __restrict__ xlb,
                                                     const float* __restrict__ att_s,
                                                     const float* __restrict__ att_d,
                                                     float* __restrict__ a_s,
                                                     float* __restrict__ a_d) {
    int b = blockIdx.x;
    if (b < SCT_BLOCKS) {
        // ---- scatter edges into CSR order ----
        int is64 = detect_is64((const int*)ei);
        int e = b * 256 + threadIdx.x;
        if (e < N_EDGES) {
            int dst = edge_at(ei, is64, (long long)N_EDGES + e);
            int src = edge_at(ei, is64, e);
            int pos = offsets[dst] + atomicAdd(&cursor[dst], 1);
            sorted_src[pos] = src;
        }
    } else {
        // ---- a_s[n,h], a_d[n,h] (wave per node) ----
        int node = (b - SCT_BLOCKS) * 4 + (threadIdx.x >> 6);
        if (node >= N_NODES) return;
        int lane = threadIdx.x & 63;
        int hd = lane >> 4;
        uint4 r = *(const uint4*)&xlb[(size_t)node * HC + lane * 8];
        float f[8];
        bf8_decode(r, f);
        float4 s0 = *(const float4*)&att_s[lane * 8];
        float4 s1 = *(const float4*)&att_s[lane * 8 + 4];
        float4 d0 = *(const float4*)&att_d[lane * 8];
        float4 d1 = *(const float4*)&att_d[lane * 8 + 4];
        float s = f[0]*s0.x + f[1]*s0.y + f[2]*s0.z + f[3]*s0.w
                + f[4]*s1.x + f[5]*s1.y + f[6]*s1.z + f[7]*s1.w;
        float d = f[0]*d0.x + f[1]*d0.y + f[2]*d0.z + f[3]*d0.w
                + f[4]*d1.x + f[5]*d1.y + f[6]*d1.z + f[7]*d1.w;
        #pragma unroll
        for (int off = 1; off < 16; off <<= 1) {
            s += __shfl_xor(s, off, 64);
            d += __shfl_xor(d, off, 64);
        }
        if ((lane & 15) == 0) {
            a_s[node * 4 + hd] = s;
            a_d[node * 4 + hd] = d;
        }
    }
}

// ---------------- single-pass segment softmax + weighted gather ----------------
// No max subtraction (logits bounded ~|8|, fp32 exp safe; algebraically identical).
// One wave per node; lane owns channels lane*8..+7 => head = lane>>4.
// Unroll-4: all feature loads issued before weight math -> 8 loads in flight/wave.
__global__ __launch_bounds__(256) void gather_kernel(const unsigned short* __restrict__ xlb,
                                                     const float* __restrict__ a_s,
                                                     const float* __restrict__ a_d,
                                                     const int* __restrict__ offsets,
                                                     const int* __restrict__ sorted_src,
                                                     const float* __restrict__ bias,
                                                     float* __restrict__ out) {
    int node = blockIdx.x * 4 + (threadIdx.x >> 6);
    if (node >= N_NODES) return;
    int lane = threadIdx.x & 63;
    int hd = lane >> 4;
    int beg = offsets[node], end = offsets[node + 1];

    const unsigned short* xrow = xlb + lane * 8;    // lane-fixed base
    float adh = a_d[node * 4 + hd];
    float acc[8];
    float denom;
    {   // self-loop
        float w = __expf(leaky(a_s[node * 4 + hd] + adh));
        denom = w;
        uint4 r = *(const uint4*)(xrow + (size_t)node * HC);
        float f[8];
        bf8_decode(r, f);
        #pragma unroll
        for (int k = 0; k < 8; k++) acc[k] = w * f[k];
    }
    int p = beg;
    for (; p + 4 <= end; p += 4) {
        int s0 = sorted_src[p];
        int s1 = sorted_src[p + 1];
        int s2 = sorted_src[p + 2];
        int s3 = sorted_src[p + 3];
        // feature loads first: independent of the weight math, 4 in flight
        uint4 r0 = *(const uint4*)(xrow + (size_t)s0 * HC);
        uint4 r1 = *(const uint4*)(xrow + (size_t)s1 * HC);
        uint4 r2 = *(const uint4*)(xrow + (size_t)s2 * HC);
        uint4 r3 = *(const uint4*)(xrow + (size_t)s3 * HC);
        float w0 = __expf(leaky(a_s[s0 * 4 + hd] + adh));
        float w1 = __expf(leaky(a_s[s1 * 4 + hd] + adh));
        float w2 = __expf(leaky(a_s[s2 * 4 + hd] + adh));
        float w3 = __expf(leaky(a_s[s3 * 4 + hd] + adh));
        denom += (w0 + w1) + (w2 + w3);
        float f0[8], f1[8], f2[8], f3[8];
        bf8_decode(r0, f0);
        bf8_decode(r1, f1);
        bf8_decode(r2, f2);
        bf8_decode(r3, f3);
        #pragma unroll
        for (int k = 0; k < 8; k++)
            acc[k] += (w0 * f0[k] + w1 * f1[k]) + (w2 * f2[k] + w3 * f3[k]);
    }
    for (; p < end; p++) {
        int s0 = sorted_src[p];
        uint4 r0 = *(const uint4*)(xrow + (size_t)s0 * HC);
        float w0 = __expf(leaky(a_s[s0 * 4 + hd] + adh));
        denom += w0;
        float f0[8];
        bf8_decode(r0, f0);
        #pragma unroll
        for (int k = 0; k < 8; k++) acc[k] += w0 * f0[k];
    }

    float rd = 0.25f / (denom + 1e-16f);   // fold head-mean into normalize
    float v[8];
    #pragma unroll
    for (int k = 0; k < 8; k++) {
        float t = acc[k] * rd;
        t += __shfl_xor(t, 16, 64);
        t += __shfl_xor(t, 32, 64);
        v[k] = t;
    }
    if (hd == 0) {   // lanes 0..15 hold head-mean for channels lane*8..+7
        float4 b0 = *(const float4*)&bias[lane * 8];
        float4 b1 = *(const float4*)&bias[lane * 8 + 4];
        float o[8];
        o[0] = v[0] + b0.x; o[1] = v[1] + b0.y; o[2] = v[2] + b0.z; o[3] = v[3] + b0.w;
        o[4] = v[4] + b1.x; o[5] = v[5] + b1.y; o[6] = v[6] + b1.z; o[7] = v[7] + b1.w;
        #pragma unroll
        for (int k = 0; k < 8; k++) o[k] = o[k] > 0.f ? o[k] : expm1f(o[k]);
        *(float4*)&out[(size_t)node * OUT_CH + lane * 8]     = make_float4(o[0], o[1], o[2], o[3]);
        *(float4*)&out[(size_t)node * OUT_CH + lane * 8 + 4] = make_float4(o[4], o[5], o[6], o[7]);
    }
}

// ---------------- launch ----------------
extern "C" void kernel_launch(void* const* d_in, const int* in_sizes, int n_in,
                              void* d_out, int out_size, void* d_ws, size_t ws_size,
                              hipStream_t stream) {
    const float* x       = (const float*)d_in[0];
    const float* W       = (const float*)d_in[1];
    const float* att_src = (const float*)d_in[2];
    const float* att_dst = (const float*)d_in[3];
    const float* bias    = (const float*)d_in[4];
    const void*  ei      = d_in[5];
    float* out = (float*)d_out;

    char* ws = (char*)d_ws;
    size_t off = 0;
    unsigned short* xlb = (unsigned short*)(ws + off); off += (size_t)N_PAD * HC * sizeof(unsigned short);
    float* a_s     = (float*)(ws + off); off += (size_t)N_NODES * HEADS * sizeof(float);
    float* a_d     = (float*)(ws + off); off += (size_t)N_NODES * HEADS * sizeof(float);
    int* counts    = (int*)(ws + off);   off += (size_t)N_NODES * sizeof(int);
    int* cursor    = (int*)(ws + off);   off += (size_t)N_NODES * sizeof(int);   // contiguous with counts
    int* offsets   = (int*)(ws + off);   off += (size_t)(N_NODES + 1) * sizeof(int);
    off = (off + 15) & ~(size_t)15;
    int* sorted_src = (int*)(ws + off);  off += (size_t)N_EDGES * sizeof(int);
    off = (off + 15) & ~(size_t)15;
    unsigned short* xb = (unsigned short*)(ws + off); off += (size_t)N_PAD * IN_CH * sizeof(unsigned short);
    unsigned short* Wt = (unsigned short*)(ws + off); off += (size_t)IN_CH * HC * sizeof(unsigned short);

    hipMemsetAsync(counts, 0, 2u * N_NODES * sizeof(int), stream);   // counts + cursor
    fusedA_kernel<<<CVX_BLOCKS + CVW_BLOCKS + CNT_BLOCKS, 256, 0, stream>>>(x, W, xb, Wt, ei, counts);
    gemm_kernel<<<dim3(HC / 128, N_PAD / 128), 256, 0, stream>>>(xb, Wt, xlb);
    scan_kernel<<<1, 1024, 0, stream>>>(counts, offsets);
    fusedB_kernel<<<SCT_BLOCKS + ATT_BLOCKS, 256, 0, stream>>>(ei, offsets, cursor, sorted_src,
                                                               xlb, att_src, att_dst, a_s, a_d);
    gather_kernel<<<(N_NODES + 3) / 4, 256, 0, stream>>>(xlb, a_s, a_d, offsets, sorted_src, bias, out);
}

// Round 5
// 215.312 us; speedup vs baseline: 1.9177x; 1.0075x over previous
//
#include <hip/hip_runtime.h>
#include <math.h>

#define N_NODES 20000
#define N_PAD 20096            // N_NODES rounded up to 128 (GEMM M-tile)
#define N_EDGES 320000
#define IN_CH 512
#define HEADS 4
#define OUT_CH 128
#define HC 512                 // HEADS*OUT_CH
#define NEG_SLOPE 0.2f

// fused-kernel block partitions
#define CVX_BLOCKS 5024        // N_PAD*IN_CH/8/256
#define CVW_BLOCKS 64          // (IN_CH/64)*(HC/64)
#define CNT_BLOCKS 1250        // N_EDGES/256
#define ATT_BLOCKS 1250        // N_NODES/16 (wave per node, 16 waves/block)

typedef __attribute__((ext_vector_type(8))) short short8;
typedef __attribute__((ext_vector_type(4))) float float4v;

// ---------------- edge-index dtype detection (inline, deterministic) ----------------
__device__ __forceinline__ int detect_is64(const int* __restrict__ ei32) {
    int is64 = 1;
    #pragma unroll
    for (int i = 0; i < 32; i++) is64 &= (ei32[2 * i + 1] == 0);
    return is64;
}

__device__ __forceinline__ int edge_at(const void* ei, int is64, long long idx) {
    return is64 ? (int)((const long long*)ei)[idx] : ((const int*)ei)[idx];
}

__device__ __forceinline__ unsigned short f2bf(float f) {
    union { float f; unsigned u; } v; v.f = f;
    unsigned r = v.u + 0x7fffu + ((v.u >> 16) & 1u);   // RNE
    return (unsigned short)(r >> 16);
}

// decode 8 packed bf16 (uint4) -> 8 floats
__device__ __forceinline__ void bf8_decode(uint4 r, float* f) {
    f[0] = __uint_as_float(r.x << 16); f[1] = __uint_as_float(r.x & 0xffff0000u);
    f[2] = __uint_as_float(r.y << 16); f[3] = __uint_as_float(r.y & 0xffff0000u);
    f[4] = __uint_as_float(r.z << 16); f[5] = __uint_as_float(r.z & 0xffff0000u);
    f[6] = __uint_as_float(r.w << 16); f[7] = __uint_as_float(r.w & 0xffff0000u);
}

__device__ __forceinline__ float leaky(float t) { return t > 0.f ? t : NEG_SLOPE * t; }

// pick w[hd] from a float4 of per-head weights (hd in 0..3) without scratch
__device__ __forceinline__ float sel_head(float4 w, int hd) {
    float lo = (hd & 1) ? w.y : w.x;
    float hi = (hd & 1) ? w.w : w.z;
    return (hd & 2) ? hi : lo;
}

// ---------------- K1: fused convert_x + convert_w(transpose) + count ----------------
__global__ __launch_bounds__(256) void fusedA_kernel(const float* __restrict__ x,
                                                     const float* __restrict__ W,
                                                     unsigned short* __restrict__ xb,
                                                     unsigned short* __restrict__ Wt,
                                                     const void* __restrict__ ei,
                                                     int* __restrict__ counts) {
    __shared__ float tile[64][65];
    int b = blockIdx.x;
    if (b < CVX_BLOCKS) {
        size_t i = ((size_t)b * 256 + threadIdx.x) * 8;
        unsigned short o[8];
        if (i < (size_t)N_NODES * IN_CH) {
            float4 f0 = *(const float4*)&x[i];
            float4 f1 = *(const float4*)&x[i + 4];
            o[0] = f2bf(f0.x); o[1] = f2bf(f0.y); o[2] = f2bf(f0.z); o[3] = f2bf(f0.w);
            o[4] = f2bf(f1.x); o[5] = f2bf(f1.y); o[6] = f2bf(f1.z); o[7] = f2bf(f1.w);
        } else {
            for (int k = 0; k < 8; k++) o[k] = 0;
        }
        *(short8*)&xb[i] = *(short8*)o;
    } else if (b < CVX_BLOCKS + CVW_BLOCKS) {
        int idx = b - CVX_BLOCKS;
        int k0 = (idx & 7) * 64, n0 = (idx >> 3) * 64;
        int t = threadIdx.x, r = t >> 6, c = t & 63;
        for (int rr = r; rr < 64; rr += 4)
            tile[rr][c] = W[(size_t)(k0 + rr) * HC + n0 + c];
        __syncthreads();
        for (int rr = r; rr < 64; rr += 4)
            Wt[(size_t)(n0 + rr) * IN_CH + k0 + c] = f2bf(tile[c][rr]);
    } else {
        int is64 = detect_is64((const int*)ei);
        int e = (b - CVX_BLOCKS - CVW_BLOCKS) * 256 + threadIdx.x;
        if (e < N_EDGES) {
            int dst = edge_at(ei, is64, (long long)N_EDGES + e);
            atomicAdd(&counts[dst], 1);
        }
    }
}

// ---------------- bf16 MFMA GEMM: xlb[M,N](bf16) = A[M,K] @ Wt[N,K]^T ----------------
__global__ __launch_bounds__(256) void gemm_kernel(const unsigned short* __restrict__ A,
                                                   const unsigned short* __restrict__ Bt,
                                                   unsigned short* __restrict__ Cb) {
    __shared__ __align__(16) unsigned short As[128 * 32];
    __shared__ __align__(16) unsigned short Bs[128 * 32];
    const int bm = blockIdx.y * 128;
    const int bn = blockIdx.x * 128;
    const int t = threadIdx.x;
    const int wv = t >> 6, lane = t & 63;
    const int wm = wv & 1, wn = wv >> 1;
    const int lm = lane & 15, lk = lane >> 4;

    float4v acc[4][4];
    #pragma unroll
    for (int i = 0; i < 4; i++)
        #pragma unroll
        for (int j = 0; j < 4; j++) acc[i][j] = (float4v){0.f, 0.f, 0.f, 0.f};

    const int srow = t >> 2;
    const int skof = (t & 3) * 8;

    for (int k0 = 0; k0 < IN_CH; k0 += 32) {
        __syncthreads();
        #pragma unroll
        for (int q = 0; q < 2; q++) {
            const unsigned short* gA = A + (size_t)(bm + q * 64 + srow) * IN_CH + k0 + skof;
            const unsigned short* gB = Bt + (size_t)(bn + q * 64 + srow) * IN_CH + k0 + skof;
            __builtin_amdgcn_global_load_lds((const __attribute__((address_space(1))) void*)gA,
                                             (__attribute__((address_space(3))) void*)&As[q * 2048 + t * 8], 16, 0, 0);
            __builtin_amdgcn_global_load_lds((const __attribute__((address_space(1))) void*)gB,
                                             (__attribute__((address_space(3))) void*)&Bs[q * 2048 + t * 8], 16, 0, 0);
        }
        __syncthreads();

        short8 af[4], bf[4];
        #pragma unroll
        for (int i = 0; i < 4; i++)
            af[i] = *(const short8*)&As[(wm * 64 + i * 16 + lm) * 32 + lk * 8];
        #pragma unroll
        for (int j = 0; j < 4; j++)
            bf[j] = *(const short8*)&Bs[(wn * 64 + j * 16 + lm) * 32 + lk * 8];
        #pragma unroll
        for (int i = 0; i < 4; i++)
            #pragma unroll
            for (int j = 0; j < 4; j++)
                acc[i][j] = __builtin_amdgcn_mfma_f32_16x16x32_bf16(af[i], bf[j], acc[i][j], 0, 0, 0);
    }

    #pragma unroll
    for (int i = 0; i < 4; i++) {
        #pragma unroll
        for (int r = 0; r < 4; r++) {
            int row = bm + wm * 64 + i * 16 + lk * 4 + r;
            if (row < N_NODES) {
                #pragma unroll
                for (int j = 0; j < 4; j++) {
                    int col = bn + wn * 64 + j * 16 + lm;
                    Cb[(size_t)row * HC + col] = f2bf(acc[i][j][r]);
                }
            }
        }
    }
}

// ---------------- K3: fused scan (block 0) + attention halves (blocks 1..) ----------------
__global__ __launch_bounds__(1024) void scanattn_kernel(const int* __restrict__ counts,
                                                        int* __restrict__ offsets,
                                                        const unsigned short* __restrict__ xlb,
                                                        const float* __restrict__ att_s,
                                                        const float* __restrict__ att_d,
                                                        float* __restrict__ a_s,
                                                        float* __restrict__ a_d) {
    int b = blockIdx.x;
    if (b == 0) {
        // chunked exclusive scan: counts -> offsets
        const int CHUNK = 20;                 // 1024*20 = 20480 >= N_NODES
        int tid = threadIdx.x;
        int base = tid * CHUNK;
        int c[CHUNK];
        #pragma unroll
        for (int k = 0; k < CHUNK; k++) {
            int i = base + k;
            c[k] = (i < N_NODES) ? counts[i] : 0;
        }
        int pre[CHUNK];
        int sum = 0;
        #pragma unroll
        for (int k = 0; k < CHUNK; k++) { pre[k] = sum; sum += c[k]; }

        int lane = tid & 63, wvv = tid >> 6;
        int s = sum;
        #pragma unroll
        for (int off = 1; off < 64; off <<= 1) {
            int u = __shfl_up(s, off, 64);
            if (lane >= off) s += u;
        }
        __shared__ int wsum[16];
        if (lane == 63) wsum[wvv] = s;
        __syncthreads();
        if (tid < 16) {
            int u = wsum[tid];
            #pragma unroll
            for (int off = 1; off < 16; off <<= 1) {
                int w = __shfl_up(u, off, 64);
                if (tid >= off) u += w;
            }
            wsum[tid] = u;
        }
        __syncthreads();
        int wbase = (wvv == 0) ? 0 : wsum[wvv - 1];
        int excl = wbase + s - sum;
        #pragma unroll
        for (int k = 0; k < CHUNK; k++) {
            int i = base + k;
            if (i < N_NODES) offsets[i] = excl + pre[k];
        }
        if (tid == 1023) offsets[N_NODES] = wbase + s;
    } else {
        // a_s[n,h], a_d[n,h] — wave per node, 16 nodes per 1024-thread block
        int node = (b - 1) * 16 + (threadIdx.x >> 6);
        if (node >= N_NODES) return;
        int lane = threadIdx.x & 63;
        int hd = lane >> 4;
        uint4 r = *(const uint4*)&xlb[(size_t)node * HC + lane * 8];
        float f[8];
        bf8_decode(r, f);
        float4 s0 = *(const float4*)&att_s[lane * 8];
        float4 s1 = *(const float4*)&att_s[lane * 8 + 4];
        float4 d0 = *(const float4*)&att_d[lane * 8];
        float4 d1 = *(const float4*)&att_d[lane * 8 + 4];
        float s = f[0]*s0.x + f[1]*s0.y + f[2]*s0.z + f[3]*s0.w
                + f[4]*s1.x + f[5]*s1.y + f[6]*s1.z + f[7]*s1.w;
        float d = f[0]*d0.x + f[1]*d0.y + f[2]*d0.z + f[3]*d0.w
                + f[4]*d1.x + f[5]*d1.y + f[6]*d1.z + f[7]*d1.w;
        #pragma unroll
        for (int off = 1; off < 16; off <<= 1) {
            s += __shfl_xor(s, off, 64);
            d += __shfl_xor(d, off, 64);
        }
        if ((lane & 15) == 0) {
            a_s[node * 4 + hd] = s;
            a_d[node * 4 + hd] = d;
        }
    }
}

// ---------------- K4: scatter + per-edge weights ----------------
// Computes w[e,h] = exp(leaky(a_s[src,h]+a_d[dst,h])) here so gather's per-edge
// critical path is just row-load -> fma (weights become uniform s_loads there).
__global__ __launch_bounds__(256) void scatterw_kernel(const void* __restrict__ ei,
                                                       const int* __restrict__ offsets,
                                                       int* __restrict__ cursor,
                                                       int* __restrict__ sorted_src,
                                                       const float* __restrict__ a_s,
                                                       const float* __restrict__ a_d,
                                                       float* __restrict__ edge_w) {
    int is64 = detect_is64((const int*)ei);
    int e = blockIdx.x * 256 + threadIdx.x;
    if (e < N_EDGES) {
        int dst = edge_at(ei, is64, (long long)N_EDGES + e);
        int src = edge_at(ei, is64, e);
        int pos = offsets[dst] + atomicAdd(&cursor[dst], 1);
        sorted_src[pos] = src;
        float4 as4 = *(const float4*)&a_s[src * 4];
        float4 ad4 = *(const float4*)&a_d[dst * 4];
        float4 w;
        w.x = __expf(leaky(as4.x + ad4.x));
        w.y = __expf(leaky(as4.y + ad4.y));
        w.z = __expf(leaky(as4.z + ad4.z));
        w.w = __expf(leaky(as4.w + ad4.w));
        *(float4*)&edge_w[(size_t)pos * 4] = w;
    }
}

// ---------------- segment softmax + weighted gather ----------------
// 2 waves per node (alternating 4-edge chunks), partials combined via LDS.
// No max subtraction (logits bounded ~|8|; fp32 exp safe; algebraically identical).
// Lane owns channels lane*8..+7 => head = lane>>4. Weights/indices are
// wave-uniform (scalar loads); only row loads use the vector-memory pipe.
__global__ __launch_bounds__(256) void gather_kernel(const unsigned short* __restrict__ xlb,
                                                     const float* __restrict__ a_s,
                                                     const float* __restrict__ a_d,
                                                     const int* __restrict__ offsets,
                                                     const int* __restrict__ sorted_src,
                                                     const float* __restrict__ edge_w,
                                                     const float* __restrict__ bias,
                                                     float* __restrict__ out) {
    __shared__ float cl[2][64][9];
    int wv = threadIdx.x >> 6;
    int nib = wv >> 1;                  // node in block (0..1)
    int sub = wv & 1;                   // which half-wave of the node
    int node = blockIdx.x * 2 + nib;    // grid = N_NODES/2, always < N_NODES
    int lane = threadIdx.x & 63;
    int hd = lane >> 4;
    int beg = offsets[node], end = offsets[node + 1];

    const unsigned short* xrow = xlb + lane * 8;
    float acc[8] = {0, 0, 0, 0, 0, 0, 0, 0};
    float denom = 0.f;

    if (sub == 0) {   // self-loop
        float4 as4 = *(const float4*)&a_s[node * 4];
        float4 ad4 = *(const float4*)&a_d[node * 4];
        float4 ws;
        ws.x = __expf(leaky(as4.x + ad4.x));
        ws.y = __expf(leaky(as4.y + ad4.y));
        ws.z = __expf(leaky(as4.z + ad4.z));
        ws.w = __expf(leaky(as4.w + ad4.w));
        float w = sel_head(ws, hd);
        denom = w;
        uint4 r = *(const uint4*)(xrow + (size_t)node * HC);
        float f[8];
        bf8_decode(r, f);
        #pragma unroll
        for (int k = 0; k < 8; k++) acc[k] = w * f[k];
    }

    for (int c0 = beg + sub * 4; c0 < end; c0 += 8) {
        int n = end - c0;
        if (n >= 4) {
            int s0 = sorted_src[c0];
            int s1 = sorted_src[c0 + 1];
            int s2 = sorted_src[c0 + 2];
            int s3 = sorted_src[c0 + 3];
            uint4 r0 = *(const uint4*)(xrow + (size_t)s0 * HC);
            uint4 r1 = *(const uint4*)(xrow + (size_t)s1 * HC);
            uint4 r2 = *(const uint4*)(xrow + (size_t)s2 * HC);
            uint4 r3 = *(const uint4*)(xrow + (size_t)s3 * HC);
            float4 wa = *(const float4*)&edge_w[(size_t)c0 * 4];
            float4 wb = *(const float4*)&edge_w[(size_t)(c0 + 1) * 4];
            float4 wc = *(const float4*)&edge_w[(size_t)(c0 + 2) * 4];
            float4 wd = *(const float4*)&edge_w[(size_t)(c0 + 3) * 4];
            float w0 = sel_head(wa, hd), w1 = sel_head(wb, hd);
            float w2 = sel_head(wc, hd), w3 = sel_head(wd, hd);
            denom += (w0 + w1) + (w2 + w3);
            float f0[8], f1[8], f2[8], f3[8];
            bf8_decode(r0, f0);
            bf8_decode(r1, f1);
            bf8_decode(r2, f2);
            bf8_decode(r3, f3);
            #pragma unroll
            for (int k = 0; k < 8; k++)
                acc[k] += (w0 * f0[k] + w1 * f1[k]) + (w2 * f2[k] + w3 * f3[k]);
        } else {
            for (int j = 0; j < n; j++) {
                int s0 = sorted_src[c0 + j];
                uint4 r0 = *(const uint4*)(xrow + (size_t)s0 * HC);
                float4 wa = *(const float4*)&edge_w[(size_t)(c0 + j) * 4];
                float w0 = sel_head(wa, hd);
                denom += w0;
                float f0[8];
                bf8_decode(r0, f0);
                #pragma unroll
                for (int k = 0; k < 8; k++) acc[k] += w0 * f0[k];
            }
        }
    }

    if (sub == 1) {
        #pragma unroll
        for (int k = 0; k < 8; k++) cl[nib][lane][k] = acc[k];
        cl[nib][lane][8] = denom;
    }
    __syncthreads();
    if (sub == 0) {
        #pragma unroll
        for (int k = 0; k < 8; k++) acc[k] += cl[nib][lane][k];
        denom += cl[nib][lane][8];

        float rd = 0.25f / (denom + 1e-16f);   // fold head-mean into normalize
        float v[8];
        #pragma unroll
        for (int k = 0; k < 8; k++) {
            float t = acc[k] * rd;
            t += __shfl_xor(t, 16, 64);
            t += __shfl_xor(t, 32, 64);
            v[k] = t;
        }
        if (hd == 0) {
            float4 b0 = *(const float4*)&bias[lane * 8];
            float4 b1 = *(const float4*)&bias[lane * 8 + 4];
            float o[8];
            o[0] = v[0] + b0.x; o[1] = v[1] + b0.y; o[2] = v[2] + b0.z; o[3] = v[3] + b0.w;
            o[4] = v[4] + b1.x; o[5] = v[5] + b1.y; o[6] = v[6] + b1.z; o[7] = v[7] + b1.w;
            #pragma unroll
            for (int k = 0; k < 8; k++) o[k] = o[k] > 0.f ? o[k] : expm1f(o[k]);
            *(float4*)&out[(size_t)node * OUT_CH + lane * 8]     = make_float4(o[0], o[1], o[2], o[3]);
            *(float4*)&out[(size_t)node * OUT_CH + lane * 8 + 4] = make_float4(o[4], o[5], o[6], o[7]);
        }
    }
}

// ---------------- launch ----------------
extern "C" void kernel_launch(void* const* d_in, const int* in_sizes, int n_in,
                              void* d_out, int out_size, void* d_ws, size_t ws_size,
                              hipStream_t stream) {
    const float* x       = (const float*)d_in[0];
    const float* W       = (const float*)d_in[1];
    const float* att_src = (const float*)d_in[2];
    const float* att_dst = (const float*)d_in[3];
    const float* bias    = (const float*)d_in[4];
    const void*  ei      = d_in[5];
    float* out = (float*)d_out;

    char* ws = (char*)d_ws;
    size_t off = 0;
    unsigned short* xlb = (unsigned short*)(ws + off); off += (size_t)N_PAD * HC * sizeof(unsigned short);
    float* a_s     = (float*)(ws + off); off += (size_t)N_NODES * HEADS * sizeof(float);
    float* a_d     = (float*)(ws + off); off += (size_t)N_NODES * HEADS * sizeof(float);
    int* counts    = (int*)(ws + off);   off += (size_t)N_NODES * sizeof(int);
    int* cursor    = (int*)(ws + off);   off += (size_t)N_NODES * sizeof(int);   // contiguous with counts
    int* offsets   = (int*)(ws + off);   off += (size_t)(N_NODES + 1) * sizeof(int);
    off = (off + 15) & ~(size_t)15;
    int* sorted_src = (int*)(ws + off);  off += (size_t)N_EDGES * sizeof(int);
    off = (off + 15) & ~(size_t)15;
    float* edge_w  = (float*)(ws + off); off += (size_t)N_EDGES * HEADS * sizeof(float);
    unsigned short* xb = (unsigned short*)(ws + off); off += (size_t)N_PAD * IN_CH * sizeof(unsigned short);
    unsigned short* Wt = (unsigned short*)(ws + off); off += (size_t)IN_CH * HC * sizeof(unsigned short);

    hipMemsetAsync(counts, 0, 2u * N_NODES * sizeof(int), stream);   // counts + cursor
    fusedA_kernel<<<CVX_BLOCKS + CVW_BLOCKS + CNT_BLOCKS, 256, 0, stream>>>(x, W, xb, Wt, ei, counts);
    gemm_kernel<<<dim3(HC / 128, N_PAD / 128), 256, 0, stream>>>(xb, Wt, xlb);
    scanattn_kernel<<<1 + ATT_BLOCKS, 1024, 0, stream>>>(counts, offsets, xlb, att_src, att_dst, a_s, a_d);
    scatterw_kernel<<<(N_EDGES + 255) / 256, 256, 0, stream>>>(ei, offsets, cursor, sorted_src, a_s, a_d, edge_w);
    gather_kernel<<<N_NODES / 2, 256, 0, stream>>>(xlb, a_s, a_d, offsets, sorted_src, edge_w, bias, out);
}